// Round 2
// baseline (632.261 us; speedup 1.0000x reference)
//
#include <hip/hip_runtime.h>

#define NN 50000
#define NE 1000000
#define DD 64
#define EPSV 1e-5f

// ---------------------------------------------------------------------------
// Detect whether edge_index is int64 or int32 (JAX x64 flag ambiguity).
// Interpreted as int64: if any sampled value is outside [0, N), data is int32.
// ---------------------------------------------------------------------------
__global__ void detect_idx_kernel(const void* __restrict__ idx, int* __restrict__ flag,
                                  int nsample, int n_nodes) {
    const long long* p = (const long long*)idx;
    int bad = 0;
    for (int i = threadIdx.x; i < nsample; i += blockDim.x) {
        long long v = p[i];
        if (v < 0 || v >= (long long)n_nodes) bad = 1;
    }
    __shared__ int sbad;
    if (threadIdx.x == 0) sbad = 0;
    __syncthreads();
    if (bad) atomicOr(&sbad, 1);
    __syncthreads();
    if (threadIdx.x == 0) *flag = sbad ? 0 : 1;  // 1 => int64, 0 => int32
}

// ---------------------------------------------------------------------------
// Edge scatter: one 64-lane wave per edge (lane = feature dim).
//   mi[end]   += e * x[start]
//   mo[start] += e * x[end]
// 2-deep software pipeline on the edge loop to hide idx->gather latency.
// ---------------------------------------------------------------------------
__global__ __launch_bounds__(256) void scatter_kernel(
    const float* __restrict__ x, const float* __restrict__ e,
    const void* __restrict__ idx, const int* __restrict__ flag,
    float* __restrict__ mi, float* __restrict__ mo, int n_edges) {
    const int lane  = threadIdx.x & 63;
    const int slot  = (blockIdx.x * blockDim.x + threadIdx.x) >> 6;
    const int nslot = (gridDim.x * blockDim.x) >> 6;
    const bool is64 = (*flag != 0);
    const long long* p64 = (const long long*)idx;
    const int*       p32 = (const int*)idx;

    int ed = slot;
    if (ed >= n_edges) return;

    // prologue: fetch edge `ed`
    int s, t;
    if (is64) { s = (int)p64[ed]; t = (int)p64[n_edges + ed]; }
    else      { s = p32[ed];      t = p32[n_edges + ed]; }
    float w = e[ed];

    for (; ed < n_edges; ) {
        int ed2 = ed + nslot;
        int s2 = 0, t2 = 0; float w2 = 0.0f;
        if (ed2 < n_edges) {
            if (is64) { s2 = (int)p64[ed2]; t2 = (int)p64[n_edges + ed2]; }
            else      { s2 = p32[ed2];      t2 = p32[n_edges + ed2]; }
            w2 = e[ed2];
        }
        float xs = x[s * DD + lane];
        float xt = x[t * DD + lane];
        unsafeAtomicAdd(&mi[t * DD + lane], w * xs);
        unsafeAtomicAdd(&mo[s * DD + lane], w * xt);
        ed = ed2; s = s2; t = t2; w = w2;
    }
}

// ---------------------------------------------------------------------------
// Fused 4-layer MLP + LayerNorm + ReLU.
// All weights in LDS. Each wave processes 4 nodes at a time; per-wave LDS
// h-buffer laid out [k][m] (float4 across the 4 nodes) so the inner dot
// product reads one broadcast float4 (h) + one conflict-free b32 (W) per k.
// LayerNorm = 64-lane shfl_xor tree, two-pass (mean, then centered var).
// ---------------------------------------------------------------------------
#define NWAVES 16
#define NPW 4  // nodes per wave-pass

__global__ __launch_bounds__(1024, 4) void fused_mlp_kernel(
    const float* __restrict__ mi, const float* __restrict__ mo, const float* __restrict__ x,
    const float* __restrict__ W1, const float* __restrict__ b1, const float* __restrict__ g1, const float* __restrict__ bt1,
    const float* __restrict__ W2, const float* __restrict__ b2, const float* __restrict__ g2, const float* __restrict__ bt2,
    const float* __restrict__ W3, const float* __restrict__ b3, const float* __restrict__ g3, const float* __restrict__ bt3,
    const float* __restrict__ W4, const float* __restrict__ b4, const float* __restrict__ g4, const float* __restrict__ bt4,
    float* __restrict__ out, int n_nodes) {

    __shared__ float sW1[192 * 64];
    __shared__ float sW2[64 * 64];
    __shared__ float sW3[64 * 64];
    __shared__ float sW4[64 * 64];
    __shared__ float sB[4][3][64];           // [layer][b,g,bt][feat]
    __shared__ float sH[NWAVES][192 * NPW];  // per-wave h buffer, [k][m]

    const int tid = threadIdx.x;
    for (int i = tid; i < 192 * 64; i += 1024) sW1[i] = W1[i];
    for (int i = tid; i < 64 * 64; i += 1024) { sW2[i] = W2[i]; sW3[i] = W3[i]; sW4[i] = W4[i]; }
    if (tid < 64) {
        int j = tid;
        sB[0][0][j] = b1[j]; sB[0][1][j] = g1[j]; sB[0][2][j] = bt1[j];
        sB[1][0][j] = b2[j]; sB[1][1][j] = g2[j]; sB[1][2][j] = bt2[j];
        sB[2][0][j] = b3[j]; sB[2][1][j] = g3[j]; sB[2][2][j] = bt3[j];
        sB[3][0][j] = b4[j]; sB[3][1][j] = g4[j]; sB[3][2][j] = bt4[j];
    }
    __syncthreads();

    const int wid  = tid >> 6;
    const int lane = tid & 63;
    const int gw   = blockIdx.x * NWAVES + wid;
    const int nw   = gridDim.x * NWAVES;
    float4* sH4 = (float4*)&sH[wid][0];  // 192 float4 slots

    const int ngroups = (n_nodes + NPW - 1) / NPW;
    for (int grp = gw; grp < ngroups; grp += nw) {
        const int n0 = grp * NPW;

        // ---- stage [mi|mo|x] for 4 nodes into per-wave LDS, layout [k][m]
        float ami[NPW], amo[NPW], ax[NPW];
        #pragma unroll
        for (int m = 0; m < NPW; ++m) {
            int n = n0 + m; if (n >= n_nodes) n = n_nodes - 1;
            ami[m] = mi[n * DD + lane];
            amo[m] = mo[n * DD + lane];
            ax[m]  = x[n * DD + lane];
        }
        sH4[lane]       = make_float4(ami[0], ami[1], ami[2], ami[3]);
        sH4[64 + lane]  = make_float4(amo[0], amo[1], amo[2], amo[3]);
        sH4[128 + lane] = make_float4(ax[0], ax[1], ax[2], ax[3]);
        // wave-synchronous: DS ops within one wave retire in program order;
        // the compiler inserts the lgkmcnt wait (same LDS array => may-alias).

        float acc[NPW];

        // ---- layer 1: 192-k dot product
        {
            float bj = sB[0][0][lane];
            #pragma unroll
            for (int m = 0; m < NPW; ++m) acc[m] = bj;
            #pragma unroll 4
            for (int k = 0; k < 192; ++k) {
                float4 hk = sH4[k];
                float  w  = sW1[k * 64 + lane];
                acc[0] = fmaf(w, hk.x, acc[0]);
                acc[1] = fmaf(w, hk.y, acc[1]);
                acc[2] = fmaf(w, hk.z, acc[2]);
                acc[3] = fmaf(w, hk.w, acc[3]);
            }
            float gj = sB[0][1][lane], btj = sB[0][2][lane];
            #pragma unroll
            for (int m = 0; m < NPW; ++m) {
                float s = acc[m];
                #pragma unroll
                for (int off = 32; off; off >>= 1) s += __shfl_xor(s, off, 64);
                float mu = s * (1.0f / 64.0f);
                float d  = acc[m] - mu;
                float s2 = d * d;
                #pragma unroll
                for (int off = 32; off; off >>= 1) s2 += __shfl_xor(s2, off, 64);
                float v = d * rsqrtf(s2 * (1.0f / 64.0f) + EPSV) * gj + btj;
                acc[m] = v > 0.0f ? v : 0.0f;
            }
            sH4[lane] = make_float4(acc[0], acc[1], acc[2], acc[3]);
        }

        // ---- layers 2..4: 64-k dot products
        const float* sWl[3] = { sW2, sW3, sW4 };
        #pragma unroll
        for (int l = 0; l < 3; ++l) {
            const float* W = sWl[l];
            float bj = sB[l + 1][0][lane];
            #pragma unroll
            for (int m = 0; m < NPW; ++m) acc[m] = bj;
            #pragma unroll 4
            for (int k = 0; k < 64; ++k) {
                float4 hk = sH4[k];
                float  w  = W[k * 64 + lane];
                acc[0] = fmaf(w, hk.x, acc[0]);
                acc[1] = fmaf(w, hk.y, acc[1]);
                acc[2] = fmaf(w, hk.z, acc[2]);
                acc[3] = fmaf(w, hk.w, acc[3]);
            }
            float gj = sB[l + 1][1][lane], btj = sB[l + 1][2][lane];
            #pragma unroll
            for (int m = 0; m < NPW; ++m) {
                float s = acc[m];
                #pragma unroll
                for (int off = 32; off; off >>= 1) s += __shfl_xor(s, off, 64);
                float mu = s * (1.0f / 64.0f);
                float d  = acc[m] - mu;
                float s2 = d * d;
                #pragma unroll
                for (int off = 32; off; off >>= 1) s2 += __shfl_xor(s2, off, 64);
                float v = d * rsqrtf(s2 * (1.0f / 64.0f) + EPSV) * gj + btj;
                acc[m] = v > 0.0f ? v : 0.0f;
            }
            if (l < 2) {
                sH4[lane] = make_float4(acc[0], acc[1], acc[2], acc[3]);
            } else {
                #pragma unroll
                for (int m = 0; m < NPW; ++m) {
                    int n = n0 + m;
                    if (n < n_nodes) out[n * DD + lane] = acc[m];
                }
            }
        }
    }
}

// ---------------------------------------------------------------------------
extern "C" void kernel_launch(void* const* d_in, const int* in_sizes, int n_in,
                              void* d_out, int out_size, void* d_ws, size_t ws_size,
                              hipStream_t stream) {
    const float* x   = (const float*)d_in[0];
    const float* e   = (const float*)d_in[1];
    const void*  idx = d_in[2];
    const float* W1 = (const float*)d_in[3],  *b1 = (const float*)d_in[4],
               * g1 = (const float*)d_in[5],  *bt1 = (const float*)d_in[6];
    const float* W2 = (const float*)d_in[7],  *b2 = (const float*)d_in[8],
               * g2 = (const float*)d_in[9],  *bt2 = (const float*)d_in[10];
    const float* W3 = (const float*)d_in[11], *b3 = (const float*)d_in[12],
               * g3 = (const float*)d_in[13], *bt3 = (const float*)d_in[14];
    const float* W4 = (const float*)d_in[15], *b4 = (const float*)d_in[16],
               * g4 = (const float*)d_in[17], *bt4 = (const float*)d_in[18];
    float* out = (float*)d_out;

    const int n_nodes = in_sizes[0] / DD;   // 50000
    const int n_edges = in_sizes[1];        // 1000000

    float* mi = (float*)d_ws;
    float* mo = mi + (size_t)n_nodes * DD;
    int* flag = (int*)(mo + (size_t)n_nodes * DD);

    // zero mi/mo (ws is poisoned 0xAA before every launch)
    hipMemsetAsync(d_ws, 0, (size_t)2 * n_nodes * DD * sizeof(float), stream);

    detect_idx_kernel<<<1, 256, 0, stream>>>(idx, flag, 4096, n_nodes);

    scatter_kernel<<<4096, 256, 0, stream>>>(x, e, idx, flag, mi, mo, n_edges);

    fused_mlp_kernel<<<256, 1024, 0, stream>>>(
        mi, mo, x,
        W1, b1, g1, bt1, W2, b2, g2, bt2, W3, b3, g3, bt3, W4, b4, g4, bt4,
        out, n_nodes);
}